// Round 12
// baseline (446.135 us; speedup 1.0000x reference)
//
#include <hip/hip_runtime.h>
#include <stdint.h>

typedef __attribute__((ext_vector_type(4))) float f32x4;
typedef __attribute__((ext_vector_type(8))) short short8v;
typedef __attribute__((ext_vector_type(8))) unsigned short ushort8v;
typedef __attribute__((ext_vector_type(4))) unsigned short ushort4v;

#define NB 8192
#define ND 2048
#define NE 8
#define NT 32   // K-tiles of 64

__device__ __forceinline__ unsigned short f2bf(float f) {
    union { float f; uint32_t u; } c; c.f = f;
    uint32_t u = c.u;
    u = u + 0x7FFFu + ((u >> 16) & 1u);   // RNE
    return (unsigned short)(u >> 16);
}

// ---- convert W_experts fp32 -> bf16 ----
__global__ __launch_bounds__(256) void cvt_w_kernel(const float* __restrict__ W,
                                                    unsigned short* __restrict__ Wb) {
    size_t i = ((size_t)blockIdx.x * 256 + threadIdx.x) * 8;
    float4 a = *(const float4*)(W + i);
    float4 b = *(const float4*)(W + i + 4);
    ushort8v o;
    o[0] = f2bf(a.x); o[1] = f2bf(a.y); o[2] = f2bf(a.z); o[3] = f2bf(a.w);
    o[4] = f2bf(b.x); o[5] = f2bf(b.y); o[6] = f2bf(b.z); o[7] = f2bf(b.w);
    *(ushort8v*)(Wb + i) = o;
}

// ---- fused: inp=concat(x,y)->bf16  +  fp64 gate logits -> top2 + softmax ----
__global__ __launch_bounds__(256) void gatecvt_kernel(const float* __restrict__ x,
                                                      const float* __restrict__ y,
                                                      const float* __restrict__ Wg,
                                                      const float* __restrict__ bg,
                                                      unsigned short* __restrict__ inpb,
                                                      int* __restrict__ tkidx,
                                                      float* __restrict__ tkg) {
    const int wave = threadIdx.x >> 6, lane = threadIdx.x & 63;
    const int b = blockIdx.x * 4 + wave;
    const float* xb = x + (size_t)b * 1024;
    const float* yb = y + (size_t)b * 1024;
    unsigned short* ob = inpb + (size_t)b * ND;
    double acc[NE] = {0, 0, 0, 0, 0, 0, 0, 0};
#pragma unroll
    for (int it = 0; it < 8; it++) {
        const int d = it * 256 + lane * 4;
        float4 v = (it < 4) ? *(const float4*)(xb + d) : *(const float4*)(yb + (d - 1024));
        ushort4v o;
        o[0] = f2bf(v.x); o[1] = f2bf(v.y); o[2] = f2bf(v.z); o[3] = f2bf(v.w);
        *(ushort4v*)(ob + d) = o;
#pragma unroll
        for (int e = 0; e < NE; e++) {
            float4 w = *(const float4*)(Wg + e * ND + d);
            acc[e] += (double)v.x * (double)w.x + (double)v.y * (double)w.y
                    + (double)v.z * (double)w.z + (double)v.w * (double)w.w;
        }
    }
#pragma unroll
    for (int e = 0; e < NE; e++) {
        double s = acc[e];
#pragma unroll
        for (int o = 32; o >= 1; o >>= 1) s += __shfl_xor(s, o, 64);
        acc[e] = s;
    }
    if (lane == 0) {
        double v0 = -1e300, v1 = -1e300; int i0 = 0, i1 = 1;
#pragma unroll
        for (int e = 0; e < NE; e++) {
            double val = acc[e] + (double)bg[e];
            if (val > v0)      { v1 = v0; i1 = i0; v0 = val; i0 = e; }
            else if (val > v1) { v1 = val; i1 = e; }
        }
        double e1 = exp(v1 - v0);
        double inv = 1.0 / (1.0 + e1);
        tkidx[b * 2]     = i0;
        tkidx[b * 2 + 1] = i1;
        tkg[b * 2]       = (float)inv;
        tkg[b * 2 + 1]   = (float)(e1 * inv);
    }
}

// ---- bucket: hist + scan + stable fill, ONE block (replaces 3 kernels) ----
// 1024 threads x 16-pair stripes; per-expert inner loops keep all reg indices
// static (rule 20). Output order = stripe-stable => deterministic.
__global__ __launch_bounds__(1024) void bucket_kernel(const int* __restrict__ tkidx,
                                                      const float* __restrict__ tkg,
                                                      int* __restrict__ meta,
                                                      int* __restrict__ tok,
                                                      float* __restrict__ gat) {
    __shared__ int hist[1024][8];   // 32 KB
    __shared__ int ebase[8];
    const int t = threadIdx.x;
    int loc[16];
#pragma unroll
    for (int i = 0; i < 16; i++) loc[i] = tkidx[t * 16 + i];
#pragma unroll
    for (int e2 = 0; e2 < 8; e2++) {
        int c = 0;
#pragma unroll
        for (int i = 0; i < 16; i++) c += (loc[i] == e2) ? 1 : 0;
        hist[t][e2] = c;
    }
    __syncthreads();
    if (t < 8) {
        int run = 0;
        for (int j = 0; j < 1024; j++) { int v = hist[j][t]; hist[j][t] = run; run += v; }
        meta[t] = run;                       // per-expert count
    }
    __syncthreads();
    if (t == 0) {
        int o = 0;
        for (int e = 0; e < 8; e++) { ebase[e] = o; meta[8 + e] = o; o += meta[e]; }
    }
    __syncthreads();
#pragma unroll
    for (int e2 = 0; e2 < 8; e2++) {
        int pp = ebase[e2] + hist[t][e2];
#pragma unroll
        for (int i = 0; i < 16; i++) {
            if (loc[i] == e2) {
                tok[pp] = t * 16 + i;        // packed pair index (token<<1)|k
                gat[pp] = tkg[t * 16 + i];
                pp++;
            }
        }
    }
}

// ---- combine: out += part1 (both fully written by the GEMM's plain stores) ----
__global__ __launch_bounds__(256) void combine_kernel(float* __restrict__ out,
                                                      const float* __restrict__ part1) {
    const size_t stride = (size_t)gridDim.x * 256 * 4;
    for (size_t i = ((size_t)blockIdx.x * 256 + threadIdx.x) * 4;
         i < (size_t)NB * ND; i += stride) {
        f32x4 a = *(const f32x4*)(out + i);
        f32x4 b = *(const f32x4*)(part1 + i);
        a = a + b;
        *(f32x4*)(out + i) = a;
    }
}

#define GLD16(gp, lp) __builtin_amdgcn_global_load_lds( \
    (const __attribute__((address_space(1))) uint32_t*)(gp), \
    (__attribute__((address_space(3))) uint32_t*)(lp), 16, 0, 0)

// ================= grouped expert GEMM: R8 structure (best measured) =================
// 256x256 tile, BK=64, 8 waves (2M x 4N). LDS: 2 bufs x 4 half-slots (A0,A1,B0,B1),
// 128 KB, 1 block/CU. One __syncthreads per K-tile (drain covered by full-tile stage-
// ahead). Body = read-once sub-phases; brA/brB hoisted (both ks B-sets loaded up front:
// second half-tile is a pure-A chain), ar reused => 48 live frag regs <= 128 budget.
template <bool STORE>
__global__ __launch_bounds__(512, 2) void moe_gemm_kernel(
    const unsigned short* __restrict__ Ab,   // [NB][ND] bf16
    const unsigned short* __restrict__ Wb,   // [NE][ND][ND] bf16 (out-major)
    const float* __restrict__ bias,          // [NE][ND]
    const int* __restrict__ tok,             // [2*NB] packed (token<<1)|k, expert-bucketed
    const float* __restrict__ gat,           // [2*NB] gate weights
    const int* __restrict__ meta,            // [0..7] counts, [8..15] offsets
    float* __restrict__ out0,                // k=0 destination (d_out)
    float* __restrict__ out1)                // k=1 destination (part1; ==out0 in atomic mode)
{
    const int e = blockIdx.z;
    const int cnt = meta[e];
    const int row0 = blockIdx.y * 256;
    if (row0 >= cnt) return;
    const int col0 = blockIdx.x * 256;
    const int base = meta[8 + e];

    // [buf][half: 0=A0 1=A1 2=B0 3=B1][128 rows][64 cols] = 128 KB
    __shared__ __align__(16) unsigned short S[2][4][128][64];

    const int tid  = threadIdx.x;
    const int wv   = tid >> 6;
    const int lane = tid & 63;
    const int wr = wv >> 2, wcn = wv & 3;
    const int fr = lane & 15, kh = lane >> 4;

    // --- staging source pointers (linear LDS dest + inverse-swizzled global chunk)
    const int srow = tid >> 3;                         // 0..63 per round
    const int cg8  = ((tid & 7) ^ (srow & 7)) * 8;     // swizzled source chunk (shorts)
    const unsigned short* wbase = Wb + (size_t)e * ND * ND;
    const unsigned short* aptr[2][2];
    const unsigned short* bptr[2][2];
#pragma unroll
    for (int h = 0; h < 2; h++)
#pragma unroll
        for (int i = 0; i < 2; i++) {
            int rt = h * 128 + i * 64 + srow;
            int gr = row0 + rt; if (gr > cnt - 1) gr = cnt - 1;
            aptr[h][i] = Ab + (size_t)(tok[base + gr] >> 1) * ND + cg8;
            bptr[h][i] = wbase + (size_t)(col0 + rt) * ND + cg8;
        }

#define STAGE_A(SB, SM, SK) do { \
    GLD16(aptr[SM][0] + (SK), (char*)&S[SB][SM][0][0] + tid * 16); \
    GLD16(aptr[SM][1] + (SK), (char*)&S[SB][SM][0][0] + tid * 16 + 8192); } while (0)
#define STAGE_B(SB, SN, SK) do { \
    GLD16(bptr[SN][0] + (SK), (char*)&S[SB][2 + SN][0][0] + tid * 16); \
    GLD16(bptr[SN][1] + (SK), (char*)&S[SB][2 + SN][0][0] + tid * 16 + 8192); } while (0)
#define STAGE_ALL(SB, SK) do { \
    STAGE_B(SB, 0, SK); STAGE_B(SB, 1, SK); STAGE_A(SB, 0, SK); STAGE_A(SB, 1, SK); } while (0)

    f32x4 acc[8][4];
#pragma unroll
    for (int m = 0; m < 8; m++)
#pragma unroll
        for (int n = 0; n < 4; n++) acc[m][n] = f32x4{0.f, 0.f, 0.f, 0.f};

    const int arow = wr * 64 + fr;        // + ml*16 within A-half
    int ca[2];
#pragma unroll
    for (int ks = 0; ks < 2; ks++) ca[ks] = ((ks * 4 + kh) ^ (fr & 7)) * 8;

#define LD_A(PB, PM, ML, KS) (*(const short8v*)&S[PB][PM][arow + (ML) * 16][ca[KS]])
#define LD_B(PB, N, KS)      (*(const short8v*)&S[PB][2 + ((N) >> 1)][wcn * 32 + ((N) & 1) * 16 + fr][ca[KS]])
#define MFMA16(MQ, AR, BR) do { \
    __builtin_amdgcn_s_setprio(1); \
    _Pragma("unroll") \
    for (int ml = 0; ml < 4; ml++) \
        _Pragma("unroll") \
        for (int n = 0; n < 4; n++) \
            acc[(MQ) * 4 + ml][n] = __builtin_amdgcn_mfma_f32_16x16x32_bf16( \
                AR[ml], BR[n], acc[(MQ) * 4 + ml][n], 0, 0, 0); \
    __builtin_amdgcn_s_setprio(0); \
    __builtin_amdgcn_sched_barrier(0); \
} while (0)

    // read-once body: both B-sets hoisted (brA=ks0, brB=ks1); ar reused across the
    // 4 clusters. Live frags = 48 regs; second half-tile is a pure-A chain.
#define BODY(PB) do { \
    short8v ar[4], brA[4], brB[4]; \
    _Pragma("unroll") \
    for (int n = 0; n < 4; n++) brA[n] = LD_B(PB, n, 0); \
    _Pragma("unroll") \
    for (int n = 0; n < 4; n++) brB[n] = LD_B(PB, n, 1); \
    _Pragma("unroll") \
    for (int i = 0; i < 4; i++) ar[i] = LD_A(PB, 0, i, 0); \
    MFMA16(0, ar, brA); \
    _Pragma("unroll") \
    for (int i = 0; i < 4; i++) ar[i] = LD_A(PB, 1, i, 0); \
    MFMA16(1, ar, brA); \
    _Pragma("unroll") \
    for (int i = 0; i < 4; i++) ar[i] = LD_A(PB, 0, i, 1); \
    MFMA16(0, ar, brB); \
    _Pragma("unroll") \
    for (int i = 0; i < 4; i++) ar[i] = LD_A(PB, 1, i, 1); \
    MFMA16(1, ar, brB); \
} while (0)

    // --- prologue: stage tile 0 into buf 0
    STAGE_ALL(0, 0);
    __syncthreads();

    for (int t = 0; t < NT; t += 2) {
        // tile t: reads buf0; stage t+1 -> buf1
        if (t + 1 < NT) STAGE_ALL(1, (t + 1) * 64);
        BODY(0);
        __syncthreads();
        // tile t+1: reads buf1; stage t+2 -> buf0
        if (t + 2 < NT) STAGE_ALL(0, (t + 2) * 64);
        BODY(1);
        __syncthreads();
    }

    // --- epilogue ---
    int   coln[4];
    float bv[4];
#pragma unroll
    for (int n = 0; n < 4; n++) {
        coln[n] = col0 + (n >> 1) * 128 + wcn * 32 + (n & 1) * 16 + fr;
        bv[n] = bias[e * ND + coln[n]];
    }
#pragma unroll
    for (int m = 0; m < 8; m++) {
        const int rbase = row0 + (m >> 2) * 128 + wr * 64 + (m & 3) * 16 + kh * 4;
#pragma unroll
        for (int j = 0; j < 4; j++) {
            const int R = rbase + j;
            if (R < cnt) {
                const int pr = tok[base + R];
                const float g = gat[base + R];
                float* orow = ((STORE && (pr & 1)) ? out1 : out0) + (size_t)(pr >> 1) * ND;
#pragma unroll
                for (int n = 0; n < 4; n++) {
                    const float v = g * (acc[m][n][j] + bv[n]);
                    if (STORE) orow[coln[n]] = v;
                    else       atomicAdd(&orow[coln[n]], v);
                }
            }
        }
    }
#undef BODY
#undef MFMA16
#undef LD_A
#undef LD_B
#undef STAGE_ALL
#undef STAGE_A
#undef STAGE_B
}

extern "C" void kernel_launch(void* const* d_in, const int* in_sizes, int n_in,
                              void* d_out, int out_size, void* d_ws, size_t ws_size,
                              hipStream_t stream) {
    const float* x  = (const float*)d_in[0];
    const float* y  = (const float*)d_in[1];
    const float* We = (const float*)d_in[2];
    const float* be = (const float*)d_in[3];
    const float* Wg = (const float*)d_in[4];
    const float* bg = (const float*)d_in[5];
    float* out = (float*)d_out;

    char* ws = (char*)d_ws;
    int*   meta  = (int*)ws;                               // [0..7] counts, [8..15] offsets
    int*   tkidx = (int*)(ws + 8192);                      // [NB*2]
    float* tkg   = (float*)(ws + 8192 + 65536);            // [NB*2]
    int*   tok   = (int*)(ws + 8192 + 2 * 65536);          // [NB*2]
    float* gat   = (float*)(ws + 8192 + 3 * 65536);        // [NB*2]
    const size_t off_inpb = 8192 + 4 * 65536;
    const size_t off_wb   = off_inpb + (size_t)NB * ND * 2;
    const size_t off_p1   = off_wb + (size_t)NE * ND * ND * 2;
    const size_t needed   = off_p1 + (size_t)NB * ND * 4;
    unsigned short* inpb = (unsigned short*)(ws + off_inpb);
    unsigned short* wb   = (unsigned short*)(ws + off_wb);
    float*          part1 = (float*)(ws + off_p1);
    const bool store_mode = (ws_size >= needed);

    cvt_w_kernel<<<16384, 256, 0, stream>>>(We, wb);
    gatecvt_kernel<<<2048, 256, 0, stream>>>(x, y, Wg, bg, inpb, tkidx, tkg);
    bucket_kernel<<<1, 1024, 0, stream>>>(tkidx, tkg, meta, tok, gat);
    if (store_mode) {
        moe_gemm_kernel<true><<<dim3(8, 32, 8), 512, 0, stream>>>(inpb, wb, be, tok, gat, meta, out, part1);
        combine_kernel<<<2048, 256, 0, stream>>>(out, part1);
    } else {
        (void)hipMemsetAsync(d_out, 0, (size_t)NB * ND * sizeof(float), stream);
        moe_gemm_kernel<false><<<dim3(8, 32, 8), 512, 0, stream>>>(inpb, wb, be, tok, gat, meta, out, out);
    }
}

// Round 13
// 290.686 us; speedup vs baseline: 1.5348x; 1.5348x over previous
//
#include <hip/hip_runtime.h>
#include <stdint.h>

typedef __attribute__((ext_vector_type(4))) float f32x4;
typedef __attribute__((ext_vector_type(8))) short short8v;
typedef __attribute__((ext_vector_type(8))) unsigned short ushort8v;
typedef __attribute__((ext_vector_type(4))) unsigned short ushort4v;

#define NB 8192
#define ND 2048
#define NE 8
#define NT 32   // K-tiles of 64

__device__ __forceinline__ unsigned short f2bf(float f) {
    union { float f; uint32_t u; } c; c.f = f;
    uint32_t u = c.u;
    u = u + 0x7FFFu + ((u >> 16) & 1u);   // RNE
    return (unsigned short)(u >> 16);
}

// ---- convert W_experts fp32 -> bf16 ----
__global__ __launch_bounds__(256) void cvt_w_kernel(const float* __restrict__ W,
                                                    unsigned short* __restrict__ Wb) {
    size_t i = ((size_t)blockIdx.x * 256 + threadIdx.x) * 8;
    float4 a = *(const float4*)(W + i);
    float4 b = *(const float4*)(W + i + 4);
    ushort8v o;
    o[0] = f2bf(a.x); o[1] = f2bf(a.y); o[2] = f2bf(a.z); o[3] = f2bf(a.w);
    o[4] = f2bf(b.x); o[5] = f2bf(b.y); o[6] = f2bf(b.z); o[7] = f2bf(b.w);
    *(ushort8v*)(Wb + i) = o;
}

// ---- fused: inp=concat(x,y)->bf16  +  fp64 gate logits -> top2 + softmax ----
__global__ __launch_bounds__(256) void gatecvt_kernel(const float* __restrict__ x,
                                                      const float* __restrict__ y,
                                                      const float* __restrict__ Wg,
                                                      const float* __restrict__ bg,
                                                      unsigned short* __restrict__ inpb,
                                                      int* __restrict__ tkidx,
                                                      float* __restrict__ tkg) {
    const int wave = threadIdx.x >> 6, lane = threadIdx.x & 63;
    const int b = blockIdx.x * 4 + wave;
    const float* xb = x + (size_t)b * 1024;
    const float* yb = y + (size_t)b * 1024;
    unsigned short* ob = inpb + (size_t)b * ND;
    double acc[NE] = {0, 0, 0, 0, 0, 0, 0, 0};
#pragma unroll
    for (int it = 0; it < 8; it++) {
        const int d = it * 256 + lane * 4;
        float4 v = (it < 4) ? *(const float4*)(xb + d) : *(const float4*)(yb + (d - 1024));
        ushort4v o;
        o[0] = f2bf(v.x); o[1] = f2bf(v.y); o[2] = f2bf(v.z); o[3] = f2bf(v.w);
        *(ushort4v*)(ob + d) = o;
#pragma unroll
        for (int e = 0; e < NE; e++) {
            float4 w = *(const float4*)(Wg + e * ND + d);
            acc[e] += (double)v.x * (double)w.x + (double)v.y * (double)w.y
                    + (double)v.z * (double)w.z + (double)v.w * (double)w.w;
        }
    }
#pragma unroll
    for (int e = 0; e < NE; e++) {
        double s = acc[e];
#pragma unroll
        for (int o = 32; o >= 1; o >>= 1) s += __shfl_xor(s, o, 64);
        acc[e] = s;
    }
    if (lane == 0) {
        double v0 = -1e300, v1 = -1e300; int i0 = 0, i1 = 1;
#pragma unroll
        for (int e = 0; e < NE; e++) {
            double val = acc[e] + (double)bg[e];
            if (val > v0)      { v1 = v0; i1 = i0; v0 = val; i0 = e; }
            else if (val > v1) { v1 = val; i1 = e; }
        }
        double e1 = exp(v1 - v0);
        double inv = 1.0 / (1.0 + e1);
        tkidx[b * 2]     = i0;
        tkidx[b * 2 + 1] = i1;
        tkg[b * 2]       = (float)inv;
        tkg[b * 2 + 1]   = (float)(e1 * inv);
    }
}

// ---- per-chunk histogram via ballot (64 chunks x 256 pairs), deterministic ----
__global__ __launch_bounds__(256) void hist_kernel(const int* __restrict__ tkidx,
                                                   int* __restrict__ hist) {
    const int p = blockIdx.x * 256 + threadIdx.x;
    const int wave = threadIdx.x >> 6, lane = threadIdx.x & 63;
    const int e = tkidx[p];
    __shared__ int cnt[4][8];
#pragma unroll
    for (int e2 = 0; e2 < 8; e2++) {
        unsigned long long m = __ballot(e == e2);
        if (lane == e2) cnt[wave][e2] = __popcll(m);
    }
    __syncthreads();
    if (threadIdx.x < 8)
        hist[blockIdx.x * 8 + threadIdx.x] =
            cnt[0][threadIdx.x] + cnt[1][threadIdx.x] + cnt[2][threadIdx.x] + cnt[3][threadIdx.x];
}

// ---- scan: chunk bases + expert totals/offsets ----
__global__ void scan_kernel(const int* __restrict__ hist, int* __restrict__ chunkbase,
                            int* __restrict__ meta) {
    __shared__ int total[8], off[8];
    const int t = threadIdx.x;
    if (t < 8) {
        int run = 0;
        for (int c = 0; c < 64; c++) { chunkbase[c * 8 + t] = run; run += hist[c * 8 + t]; }
        total[t] = run; meta[t] = run;
    }
    __syncthreads();
    if (t == 0) { int o = 0; for (int e = 0; e < 8; e++) { off[e] = o; meta[8 + e] = o; o += total[e]; } }
    __syncthreads();
    for (int i = t; i < 512; i += 64) chunkbase[i] += off[i & 7];
}

// ---- fill: stable rank within (chunk,expert) via ballot, no atomics ----
// stores the PAIR index p = (token<<1)|k so the GEMM knows which of the
// token's two experts this entry is (k selects the store destination).
__global__ __launch_bounds__(256) void fill_kernel(const int* __restrict__ tkidx,
                                                   const float* __restrict__ tkg,
                                                   const int* __restrict__ chunkbase,
                                                   int* __restrict__ tok,
                                                   float* __restrict__ gat) {
    const int p = blockIdx.x * 256 + threadIdx.x;
    const int wave = threadIdx.x >> 6, lane = threadIdx.x & 63;
    const int e = tkidx[p];
    const float g = tkg[p];
    __shared__ int cnt[4][8];
    unsigned long long mym = 0;
#pragma unroll
    for (int e2 = 0; e2 < 8; e2++) {
        unsigned long long m = __ballot(e == e2);
        if (e == e2) mym = m;
        if (lane == e2) cnt[wave][e2] = __popcll(m);
    }
    __syncthreads();
    int basep = chunkbase[blockIdx.x * 8 + e];
    for (int w = 0; w < wave; w++) basep += cnt[w][e];
    const int rank = __popcll(mym & ((1ull << lane) - 1ull));
    tok[basep + rank] = p;
    gat[basep + rank] = g;
}

// ---- combine: out += part1 (both fully written by the GEMM's plain stores) ----
__global__ __launch_bounds__(256) void combine_kernel(float* __restrict__ out,
                                                      const float* __restrict__ part1) {
    const size_t stride = (size_t)gridDim.x * 256 * 4;
    for (size_t i = ((size_t)blockIdx.x * 256 + threadIdx.x) * 4;
         i < (size_t)NB * ND; i += stride) {
        f32x4 a = *(const f32x4*)(out + i);
        f32x4 b = *(const f32x4*)(part1 + i);
        a = a + b;
        *(f32x4*)(out + i) = a;
    }
}

#define GLD16(gp, lp) __builtin_amdgcn_global_load_lds( \
    (const __attribute__((address_space(1))) uint32_t*)(gp), \
    (__attribute__((address_space(3))) uint32_t*)(lp), 16, 0, 0)

// ================= grouped expert GEMM: 1-sync-per-K-tile, low-pressure phases =================
// (exact R8 configuration — best measured: 194 us, MfmaUtil 31%)
// 256x256 tile, BK=64, 8 waves (2M x 4N). LDS: 2 bufs x 4 half-slots (A0,A1,B0,B1).
// NO intra-tile barriers; one __syncthreads per tile (stage issued a full tile ahead).
// Body = 4 read-once sub-phases reusing ar[4]/br[4] (32 live frag regs), fenced by
// sched_barrier(0) to bound liveness. setprio(1) around MFMA clusters.
template <bool STORE>
__global__ __launch_bounds__(512, 2) void moe_gemm_kernel(
    const unsigned short* __restrict__ Ab,   // [NB][ND] bf16
    const unsigned short* __restrict__ Wb,   // [NE][ND][ND] bf16 (out-major)
    const float* __restrict__ bias,          // [NE][ND]
    const int* __restrict__ tok,             // [2*NB] packed (token<<1)|k, expert-bucketed
    const float* __restrict__ gat,           // [2*NB] gate weights
    const int* __restrict__ meta,            // [0..7] counts, [8..15] offsets
    float* __restrict__ out0,                // k=0 destination (d_out)
    float* __restrict__ out1)                // k=1 destination (part1; ==out0 in atomic mode)
{
    const int e = blockIdx.z;
    const int cnt = meta[e];
    const int row0 = blockIdx.y * 256;
    if (row0 >= cnt) return;
    const int col0 = blockIdx.x * 256;
    const int base = meta[8 + e];

    // [buf][half: 0=A0 1=A1 2=B0 3=B1][128 rows][64 cols] = 128 KB
    __shared__ __align__(16) unsigned short S[2][4][128][64];

    const int tid  = threadIdx.x;
    const int wv   = tid >> 6;
    const int lane = tid & 63;
    const int wr = wv >> 2, wcn = wv & 3;
    const int fr = lane & 15, kh = lane >> 4;

    // --- staging source pointers (linear LDS dest + inverse-swizzled global chunk)
    const int srow = tid >> 3;                         // 0..63 per round
    const int cg8  = ((tid & 7) ^ (srow & 7)) * 8;     // swizzled source chunk (shorts)
    const unsigned short* wbase = Wb + (size_t)e * ND * ND;
    const unsigned short* aptr[2][2];
    const unsigned short* bptr[2][2];
#pragma unroll
    for (int h = 0; h < 2; h++)
#pragma unroll
        for (int i = 0; i < 2; i++) {
            int rt = h * 128 + i * 64 + srow;
            int gr = row0 + rt; if (gr > cnt - 1) gr = cnt - 1;
            aptr[h][i] = Ab + (size_t)(tok[base + gr] >> 1) * ND + cg8;
            bptr[h][i] = wbase + (size_t)(col0 + rt) * ND + cg8;
        }

#define STAGE_A(SB, SM, SK) do { \
    GLD16(aptr[SM][0] + (SK), (char*)&S[SB][SM][0][0] + tid * 16); \
    GLD16(aptr[SM][1] + (SK), (char*)&S[SB][SM][0][0] + tid * 16 + 8192); } while (0)
#define STAGE_B(SB, SN, SK) do { \
    GLD16(bptr[SN][0] + (SK), (char*)&S[SB][2 + SN][0][0] + tid * 16); \
    GLD16(bptr[SN][1] + (SK), (char*)&S[SB][2 + SN][0][0] + tid * 16 + 8192); } while (0)
#define STAGE_ALL(SB, SK) do { \
    STAGE_A(SB, 0, SK); STAGE_B(SB, 0, SK); STAGE_B(SB, 1, SK); STAGE_A(SB, 1, SK); } while (0)

    f32x4 acc[8][4];
#pragma unroll
    for (int m = 0; m < 8; m++)
#pragma unroll
        for (int n = 0; n < 4; n++) acc[m][n] = f32x4{0.f, 0.f, 0.f, 0.f};

    const int arow = wr * 64 + fr;        // + ml*16 within A-half
    int ca[2];
#pragma unroll
    for (int ks = 0; ks < 2; ks++) ca[ks] = ((ks * 4 + kh) ^ (fr & 7)) * 8;

#define LD_A(PB, PM, ML, KS) (*(const short8v*)&S[PB][PM][arow + (ML) * 16][ca[KS]])
#define LD_B(PB, N, KS)      (*(const short8v*)&S[PB][2 + ((N) >> 1)][wcn * 32 + ((N) & 1) * 16 + fr][ca[KS]])
#define MFMA16(MQ) do { \
    __builtin_amdgcn_s_setprio(1); \
    _Pragma("unroll") \
    for (int ml = 0; ml < 4; ml++) \
        _Pragma("unroll") \
        for (int n = 0; n < 4; n++) \
            acc[(MQ) * 4 + ml][n] = __builtin_amdgcn_mfma_f32_16x16x32_bf16( \
                ar[ml], br[n], acc[(MQ) * 4 + ml][n], 0, 0, 0); \
    __builtin_amdgcn_s_setprio(0); \
    __builtin_amdgcn_sched_barrier(0); \
} while (0)

    // 4 low-pressure read-once phases per tile; ar/br reused (32 live VGPRs)
#define BODY(PB) do { \
    short8v ar[4], br[4]; \
    _Pragma("unroll") \
    for (int i = 0; i < 4; i++) ar[i] = LD_A(PB, 0, i, 0); \
    _Pragma("unroll") \
    for (int i = 0; i < 4; i++) br[i] = LD_B(PB, i, 0); \
    MFMA16(0); \
    _Pragma("unroll") \
    for (int i = 0; i < 4; i++) ar[i] = LD_A(PB, 1, i, 0); \
    MFMA16(1); \
    _Pragma("unroll") \
    for (int i = 0; i < 4; i++) ar[i] = LD_A(PB, 0, i, 1); \
    _Pragma("unroll") \
    for (int i = 0; i < 4; i++) br[i] = LD_B(PB, i, 1); \
    MFMA16(0); \
    _Pragma("unroll") \
    for (int i = 0; i < 4; i++) ar[i] = LD_A(PB, 1, i, 1); \
    MFMA16(1); \
} while (0)

    // --- prologue: stage tile 0 into buf 0
    STAGE_ALL(0, 0);
    __syncthreads();

    for (int t = 0; t < NT; t += 2) {
        // tile t: reads buf0; stage t+1 -> buf1
        if (t + 1 < NT) STAGE_ALL(1, (t + 1) * 64);
        BODY(0);
        __syncthreads();
        // tile t+1: reads buf1; stage t+2 -> buf0
        if (t + 2 < NT) STAGE_ALL(0, (t + 2) * 64);
        BODY(1);
        __syncthreads();
    }

    // --- epilogue ---
    int   coln[4];
    float bv[4];
#pragma unroll
    for (int n = 0; n < 4; n++) {
        coln[n] = col0 + (n >> 1) * 128 + wcn * 32 + (n & 1) * 16 + fr;
        bv[n] = bias[e * ND + coln[n]];
    }
#pragma unroll
    for (int m = 0; m < 8; m++) {
        const int rbase = row0 + (m >> 2) * 128 + wr * 64 + (m & 3) * 16 + kh * 4;
#pragma unroll
        for (int j = 0; j < 4; j++) {
            const int R = rbase + j;
            if (R < cnt) {
                const int pr = tok[base + R];
                const float g = gat[base + R];
                float* orow = ((STORE && (pr & 1)) ? out1 : out0) + (size_t)(pr >> 1) * ND;
#pragma unroll
                for (int n = 0; n < 4; n++) {
                    const float v = g * (acc[m][n][j] + bv[n]);
                    if (STORE) orow[coln[n]] = v;
                    else       atomicAdd(&orow[coln[n]], v);
                }
            }
        }
    }
#undef BODY
#undef MFMA16
#undef LD_A
#undef LD_B
#undef STAGE_ALL
#undef STAGE_A
#undef STAGE_B
}

extern "C" void kernel_launch(void* const* d_in, const int* in_sizes, int n_in,
                              void* d_out, int out_size, void* d_ws, size_t ws_size,
                              hipStream_t stream) {
    const float* x  = (const float*)d_in[0];
    const float* y  = (const float*)d_in[1];
    const float* We = (const float*)d_in[2];
    const float* be = (const float*)d_in[3];
    const float* Wg = (const float*)d_in[4];
    const float* bg = (const float*)d_in[5];
    float* out = (float*)d_out;

    char* ws = (char*)d_ws;
    int*   meta  = (int*)ws;                               // [0..7] counts, [8..15] offsets
    int*   hist  = (int*)(ws + 256);                       // [64*8]
    int*   cbase = (int*)(ws + 256 + 2048);                // [64*8]
    int*   tkidx = (int*)(ws + 8192);                      // [NB*2]
    float* tkg   = (float*)(ws + 8192 + 65536);            // [NB*2]
    int*   tok   = (int*)(ws + 8192 + 2 * 65536);          // [NB*2]
    float* gat   = (float*)(ws + 8192 + 3 * 65536);        // [NB*2]
    const size_t off_inpb = 8192 + 4 * 65536;
    const size_t off_wb   = off_inpb + (size_t)NB * ND * 2;
    const size_t off_p1   = off_wb + (size_t)NE * ND * ND * 2;
    const size_t needed   = off_p1 + (size_t)NB * ND * 4;
    unsigned short* inpb = (unsigned short*)(ws + off_inpb);
    unsigned short* wb   = (unsigned short*)(ws + off_wb);
    float*          part1 = (float*)(ws + off_p1);
    const bool store_mode = (ws_size >= needed);

    cvt_w_kernel<<<16384, 256, 0, stream>>>(We, wb);
    gatecvt_kernel<<<2048, 256, 0, stream>>>(x, y, Wg, bg, inpb, tkidx, tkg);
    hist_kernel<<<64, 256, 0, stream>>>(tkidx, hist);
    scan_kernel<<<1, 64, 0, stream>>>(hist, cbase, meta);
    fill_kernel<<<64, 256, 0, stream>>>(tkidx, tkg, cbase, tok, gat);
    if (store_mode) {
        moe_gemm_kernel<true><<<dim3(8, 32, 8), 512, 0, stream>>>(inpb, wb, be, tok, gat, meta, out, part1);
        combine_kernel<<<2048, 256, 0, stream>>>(out, part1);
    } else {
        (void)hipMemsetAsync(d_out, 0, (size_t)NB * ND * sizeof(float), stream);
        moe_gemm_kernel<false><<<dim3(8, 32, 8), 512, 0, stream>>>(inpb, wb, be, tok, gat, meta, out, out);
    }
}